// Round 1
// baseline (3765.540 us; speedup 1.0000x reference)
//
#include <hip/hip_runtime.h>
#include <math.h>

#define I_IMG 3
#define S_SEQ 64
#define C_CH  512
#define H_IN  18
#define W_IN  18
#define OH 19
#define OW 19
#define NPIX 361
#define PH 22
#define PW 22
#define FT 16
#define NITER 5
#define CH_STG 8

__device__ inline float blk_reduce(float v, float* tmp) {
  #pragma unroll
  for (int o = 32; o > 0; o >>= 1) v += __shfl_down(v, o, 64);
  int lane = threadIdx.x & 63;
  int w = threadIdx.x >> 6;
  if (lane == 0) tmp[w] = v;
  __syncthreads();
  float r = 0.f;
  if (threadIdx.x == 0) {
    int nw = (blockDim.x + 63) >> 6;
    for (int k = 0; k < nw; ++k) r += tmp[k];
  }
  return r;
}

// ---------------------------------------------------------------------------
// prep: distance map -> label_map, sample_weight, a_lo, a_hi; scalars
// ---------------------------------------------------------------------------
__global__ void prep_k(const float* __restrict__ bb,
                       const float* __restrict__ label_w,
                       const float* __restrict__ mask_w,
                       const float* __restrict__ spatial_w,
                       const float* __restrict__ lsl,
                       const float* __restrict__ freg,
                       float* __restrict__ sw, float* __restrict__ lm,
                       float* __restrict__ alo, float* __restrict__ ahi,
                       float* __restrict__ scal)
{
  int n = blockIdx.x;     // n = i*S + s
  int p = threadIdx.x;
  if (n == 0 && p == 0) {
    scal[0] = expf(lsl[0]);                 // step
    scal[1] = fmaxf(freg[0] * freg[0], 1e-6f); // reg (clip at MIN_FILTER_REG^2)
  }
  if (p >= NPIX) return;
  float bx = bb[n * 4 + 0], by = bb[n * 4 + 1];
  float bw = bb[n * 4 + 2], bh = bb[n * 4 + 3];
  // center = ((xy + wh/2)/16)[::-1]; offset = 0 for even filter
  float crow = (by + bh * 0.5f) * (1.f / 16.f);
  float ccol = (bx + bw * 0.5f) * (1.f / 16.f);
  int y = p / OW, x = p - (p / OW) * OW;
  float d0 = (float)y - crow, d1 = (float)x - ccol;
  float dist = sqrtf(d0 * d0 + d1 * d1);
  float bins[5];
  #pragma unroll
  for (int b = 0; b < 4; ++b) bins[b] = fmaxf(1.f - fabsf(dist - (float)b), 0.f);
  bins[4] = fminf(fmaxf(dist - 3.f, 0.f), 1.f);
  float lmv = 0.f, mm = 0.f, sp = 0.f;
  #pragma unroll
  for (int b = 0; b < 5; ++b) {
    lmv += bins[b] * label_w[b];
    mm  += bins[b] * mask_w[b];
    sp  += bins[b] * spatial_w[b];
  }
  float tm = 1.f / (1.f + expf(-mm));  // sigmoid mask activation
  int idx = n * NPIX + p;
  lm[idx]  = lmv;
  sw[idx]  = 0.57735026918962584f * sp;   // sqrt(1/3) * spatial_weight
  alo[idx] = 0.5f * (1.f - tm);
  ahi[idx] = 0.5f * (1.f + tm);
}

// ---------------------------------------------------------------------------
// forward grouped conv, block = one (i,s). MODE 0: scores -> mask + residuals
// MODE 1: scores_grad -> per-block sum of squares (alpha_den partials)
// ---------------------------------------------------------------------------
template<int MODE>
__global__ __launch_bounds__(256) void conv_fwd_k(
    const float* __restrict__ feat, const float* __restrict__ wsrc,
    const float* __restrict__ sw, const float* __restrict__ lm,
    const float* __restrict__ alo, const float* __restrict__ ahi,
    float* __restrict__ maskio,   // MODE0: out, MODE1: in
    float* __restrict__ rout,     // MODE0 only
    float* __restrict__ den_part) // MODE1 only
{
  __shared__ float sfeat[CH_STG * PH * PW];
  __shared__ float swgt[CH_STG * FT];
  __shared__ float rtmp[4];
  int tid = threadIdx.x;
  int n = blockIdx.x;
  int s = n & 63;
  const float* fbase = feat + (size_t)n * C_CH * (H_IN * W_IN);
  const float* wbase = wsrc + (size_t)s * C_CH * FT;

  for (int idx = tid; idx < CH_STG * PH * PW; idx += 256) sfeat[idx] = 0.f;
  __syncthreads();

  int p0 = tid, p1 = tid + 256;
  int y0 = p0 / OW, x0 = p0 - (p0 / OW) * OW;
  int y1 = p1 / OW, x1 = p1 - (p1 / OW) * OW;
  bool has1 = (p1 < NPIX);
  if (!has1) { y1 = 0; x1 = 0; }
  float acc0 = 0.f, acc1 = 0.f;

  for (int c0 = 0; c0 < C_CH; c0 += CH_STG) {
    for (int idx = tid; idx < CH_STG * H_IN * W_IN; idx += 256) {
      int ch = idx / (H_IN * W_IN);
      int pix = idx - ch * (H_IN * W_IN);
      int u = pix / W_IN, v = pix - u * W_IN;
      sfeat[ch * (PH * PW) + (u + 2) * PW + (v + 2)] =
          fbase[(size_t)(c0 + ch) * (H_IN * W_IN) + pix];
    }
    for (int idx = tid; idx < CH_STG * FT; idx += 256)
      swgt[idx] = wbase[c0 * FT + idx];
    __syncthreads();

    for (int ch = 0; ch < CH_STG; ++ch) {
      float w[FT];
      #pragma unroll
      for (int t = 0; t < FT; ++t) w[t] = swgt[ch * FT + t];
      const float* fp = &sfeat[ch * (PH * PW)];
      #pragma unroll
      for (int dy = 0; dy < 4; ++dy) {
        #pragma unroll
        for (int dx = 0; dx < 4; ++dx) {
          acc0 = fmaf(fp[(y0 + dy) * PW + (x0 + dx)], w[dy * 4 + dx], acc0);
        }
      }
      if (has1) {
        #pragma unroll
        for (int dy = 0; dy < 4; ++dy) {
          #pragma unroll
          for (int dx = 0; dx < 4; ++dx) {
            acc1 = fmaf(fp[(y1 + dy) * PW + (x1 + dx)], w[dy * 4 + dx], acc1);
          }
        }
      }
    }
    __syncthreads();
  }

  if (MODE == 0) {
    {
      int idx = n * NPIX + p0;
      float lo = alo[idx], hi = ahi[idx], s_w = sw[idx], l_v = lm[idx];
      float sv = acc0;
      float sgn = (sv > 0.f) ? 1.f : ((sv < 0.f) ? -1.f : 0.f);
      float act = lo * fabsf(sv) + hi * sv;
      float msk = lo * sgn + hi;
      maskio[idx] = msk;
      rout[idx] = msk * s_w * s_w * (act - l_v);
    }
    if (has1) {
      int idx = n * NPIX + p1;
      float lo = alo[idx], hi = ahi[idx], s_w = sw[idx], l_v = lm[idx];
      float sv = acc1;
      float sgn = (sv > 0.f) ? 1.f : ((sv < 0.f) ? -1.f : 0.f);
      float act = lo * fabsf(sv) + hi * sv;
      float msk = lo * sgn + hi;
      maskio[idx] = msk;
      rout[idx] = msk * s_w * s_w * (act - l_v);
    }
  } else {
    float part = 0.f;
    {
      int idx = n * NPIX + p0;
      float sg = sw[idx] * maskio[idx] * acc0;
      part += sg * sg;
    }
    if (has1) {
      int idx = n * NPIX + p1;
      float sg = sw[idx] * maskio[idx] * acc1;
      part += sg * sg;
    }
    float tot = blk_reduce(part, rtmp);
    if (tid == 0) den_part[s * 3 + (n >> 6)] = tot;
  }
}

// ---------------------------------------------------------------------------
// transpose conv: weights_grad[s,c,dy,dx] = sum_{i,y,x} feat*r  (+ reg*w)
// block = (cblk, s); 256 threads = 16 channels x 16 taps
// ---------------------------------------------------------------------------
__global__ __launch_bounds__(256) void conv_tr_k(
    const float* __restrict__ feat, const float* __restrict__ r,
    const float* __restrict__ wcur, const float* __restrict__ scal,
    float* __restrict__ wg, float* __restrict__ num_part)
{
  __shared__ float rp[3 * 21 * 21];
  __shared__ float rtmp[4];
  int tid = threadIdx.x;
  int s = blockIdx.y;
  int cblk = blockIdx.x;
  int csub = tid >> 4, tap = tid & 15;
  int dy = tap >> 2, dx = tap & 3;
  int c = cblk * 16 + csub;

  for (int idx = tid; idx < 3 * 441; idx += 256) rp[idx] = 0.f;
  __syncthreads();
  for (int idx = tid; idx < 3 * NPIX; idx += 256) {
    int i = idx / NPIX, p = idx - i * NPIX;
    int y = p / OW, x = p - y * OW;
    rp[i * 441 + (y + 1) * 21 + (x + 1)] = r[(size_t)(i * S_SEQ + s) * NPIX + p];
  }
  __syncthreads();

  float acc = 0.f;
  #pragma unroll
  for (int i = 0; i < 3; ++i) {
    const float* fp = feat + (size_t)((i * S_SEQ + s) * C_CH + c) * (H_IN * W_IN);
    const float* rpi = &rp[i * 441 + (3 - dy) * 21 + (3 - dx)];
    for (int u = 0; u < H_IN; ++u) {
      const float* frow = fp + u * W_IN;
      const float* rrow = rpi + u * 21;
      #pragma unroll
      for (int v = 0; v < W_IN; v += 2) {
        float2 f2 = *(const float2*)(frow + v);
        acc = fmaf(f2.x, rrow[v], acc);
        acc = fmaf(f2.y, rrow[v + 1], acc);
      }
    }
  }
  float regv = scal[1];
  size_t widx = ((size_t)s * C_CH + c) * FT + tap;
  float w = acc + regv * wcur[widx];
  wg[widx] = w;
  float tot = blk_reduce(w * w, rtmp);
  if (tid == 0) num_part[s * 32 + cblk] = tot;
}

// ---------------------------------------------------------------------------
// update: alpha = num / clip(den + reg*num, 1e-8); w -= step*alpha*wg
// ---------------------------------------------------------------------------
__global__ __launch_bounds__(256) void update_k(
    float* __restrict__ wcur, const float* __restrict__ wg,
    const float* __restrict__ num_part, const float* __restrict__ den_part,
    const float* __restrict__ scal)
{
  int s = blockIdx.x;
  float num = 0.f;
  #pragma unroll
  for (int k = 0; k < 32; ++k) num += num_part[s * 32 + k];
  float den = den_part[s * 3 + 0] + den_part[s * 3 + 1] + den_part[s * 3 + 2];
  float regv = scal[1], step = scal[0];
  den = fmaxf(den + regv * num, 1e-8f);
  float sa = step * (num / den);
  for (int idx = threadIdx.x; idx < C_CH * FT; idx += 256) {
    size_t g = (size_t)s * (C_CH * FT) + idx;
    wcur[g] -= sa * wg[g];
  }
}

// ---------------------------------------------------------------------------
extern "C" void kernel_launch(void* const* d_in, const int* in_sizes, int n_in,
                              void* d_out, int out_size, void* d_ws, size_t ws_size,
                              hipStream_t stream)
{
  const float* w_in = (const float*)d_in[0];
  const float* feat = (const float*)d_in[1];
  const float* bb   = (const float*)d_in[2];
  const float* lblw = (const float*)d_in[3];
  const float* mskw = (const float*)d_in[4];
  const float* spw  = (const float*)d_in[5];
  const float* lsl  = (const float*)d_in[6];
  const float* freg = (const float*)d_in[7];

  float* base = (float*)d_ws;
  const int NMAP = I_IMG * S_SEQ * NPIX;   // 69312
  const int NW   = S_SEQ * C_CH * FT;      // 524288
  float* sw   = base;
  float* lm   = sw + NMAP;
  float* alo  = lm + NMAP;
  float* ahi  = alo + NMAP;
  float* mask = ahi + NMAP;
  float* rbuf = mask + NMAP;
  float* wcur = rbuf + NMAP;
  float* wg   = wcur + NW;
  float* nump = wg + NW;
  float* denp = nump + S_SEQ * 32;
  float* scal = denp + S_SEQ * 3;

  prep_k<<<I_IMG * S_SEQ, 384, 0, stream>>>(bb, lblw, mskw, spw, lsl, freg,
                                            sw, lm, alo, ahi, scal);
  hipMemcpyAsync(wcur, w_in, (size_t)NW * sizeof(float),
                 hipMemcpyDeviceToDevice, stream);

  for (int it = 0; it < NITER; ++it) {
    conv_fwd_k<0><<<I_IMG * S_SEQ, 256, 0, stream>>>(
        feat, wcur, sw, lm, alo, ahi, mask, rbuf, nullptr);
    conv_tr_k<<<dim3(32, S_SEQ), 256, 0, stream>>>(
        feat, rbuf, wcur, scal, wg, nump);
    conv_fwd_k<1><<<I_IMG * S_SEQ, 256, 0, stream>>>(
        feat, wg, sw, lm, alo, ahi, mask, nullptr, denp);
    update_k<<<S_SEQ, 256, 0, stream>>>(wcur, wg, nump, denp, scal);
  }
  hipMemcpyAsync(d_out, wcur, (size_t)NW * sizeof(float),
                 hipMemcpyDeviceToDevice, stream);
}

// Round 2
// 1081.948 us; speedup vs baseline: 3.4803x; 3.4803x over previous
//
#include <hip/hip_runtime.h>
#include <math.h>

#define I_IMG 3
#define S_SEQ 64
#define C_CH  512
#define H_IN  18
#define W_IN  18
#define OH 19
#define OW 19
#define NPIX 361
#define PH 22
#define PW 22
#define FT 16
#define NITER 5
#define CH_STG 8
#define CSPLIT 8
#define CPB 64   // channels per conv_fwd block

__device__ inline float blk_reduce(float v, float* tmp) {
  #pragma unroll
  for (int o = 32; o > 0; o >>= 1) v += __shfl_down(v, o, 64);
  int lane = threadIdx.x & 63;
  int w = threadIdx.x >> 6;
  if (lane == 0) tmp[w] = v;
  __syncthreads();
  float r = 0.f;
  if (threadIdx.x == 0) {
    int nw = (blockDim.x + 63) >> 6;
    for (int k = 0; k < nw; ++k) r += tmp[k];
  }
  return r;
}

// ---------------------------------------------------------------------------
// prep: distance map -> label_map, sample_weight, a_lo, a_hi; scalars
// ---------------------------------------------------------------------------
__global__ void prep_k(const float* __restrict__ bb,
                       const float* __restrict__ label_w,
                       const float* __restrict__ mask_w,
                       const float* __restrict__ spatial_w,
                       const float* __restrict__ lsl,
                       const float* __restrict__ freg,
                       float* __restrict__ sw, float* __restrict__ lm,
                       float* __restrict__ alo, float* __restrict__ ahi,
                       float* __restrict__ scal)
{
  int n = blockIdx.x;     // n = i*S + s
  int p = threadIdx.x;
  if (n == 0 && p == 0) {
    scal[0] = expf(lsl[0]);                    // step
    scal[1] = fmaxf(freg[0] * freg[0], 1e-6f); // reg
  }
  if (p >= NPIX) return;
  float bx = bb[n * 4 + 0], by = bb[n * 4 + 1];
  float bw = bb[n * 4 + 2], bh = bb[n * 4 + 3];
  float crow = (by + bh * 0.5f) * (1.f / 16.f);
  float ccol = (bx + bw * 0.5f) * (1.f / 16.f);
  int y = p / OW, x = p - (p / OW) * OW;
  float d0 = (float)y - crow, d1 = (float)x - ccol;
  float dist = sqrtf(d0 * d0 + d1 * d1);
  float bins[5];
  #pragma unroll
  for (int b = 0; b < 4; ++b) bins[b] = fmaxf(1.f - fabsf(dist - (float)b), 0.f);
  bins[4] = fminf(fmaxf(dist - 3.f, 0.f), 1.f);
  float lmv = 0.f, mm = 0.f, sp = 0.f;
  #pragma unroll
  for (int b = 0; b < 5; ++b) {
    lmv += bins[b] * label_w[b];
    mm  += bins[b] * mask_w[b];
    sp  += bins[b] * spatial_w[b];
  }
  float tm = 1.f / (1.f + expf(-mm));
  int idx = n * NPIX + p;
  lm[idx]  = lmv;
  sw[idx]  = 0.57735026918962584f * sp;   // sqrt(1/3) * spatial_weight
  alo[idx] = 0.5f * (1.f - tm);
  ahi[idx] = 0.5f * (1.f + tm);
}

// ---------------------------------------------------------------------------
// forward grouped conv, channel-split partials.
// grid (I*S, CSPLIT), block 192 = 3 waves. Thread = horizontal pixel pair.
// ---------------------------------------------------------------------------
__global__ __launch_bounds__(192) void conv_fwd_part_k(
    const float* __restrict__ feat, const float* __restrict__ wsrc,
    float* __restrict__ part)
{
  __shared__ __align__(16) float sfeat[CH_STG * PH * PW];
  int tid = threadIdx.x;
  int n = blockIdx.x;
  int s = n & 63;
  int kc = blockIdx.y;
  const float* fbase = feat + ((size_t)n * C_CH + kc * CPB) * (H_IN * W_IN);
  const float* wbase = wsrc + ((size_t)s * C_CH + kc * CPB) * FT;

  for (int idx = tid; idx < CH_STG * PH * PW; idx += 192) sfeat[idx] = 0.f;
  __syncthreads();

  int py = tid / 10;          // 0..18 for tid<190
  int px = (tid % 10) * 2;    // 0,2,..,18
  bool act = tid < 190;
  float acc0 = 0.f, acc1 = 0.f;

  for (int c0 = 0; c0 < CPB; c0 += CH_STG) {
    for (int idx = tid; idx < CH_STG * H_IN * W_IN; idx += 192) {
      int ch = idx / (H_IN * W_IN);
      int pix = idx - ch * (H_IN * W_IN);
      int u = pix / W_IN, v = pix - u * W_IN;
      sfeat[ch * (PH * PW) + (u + 2) * PW + (v + 2)] =
          fbase[(size_t)(c0 + ch) * (H_IN * W_IN) + pix];
    }
    __syncthreads();

    for (int ch = 0; ch < CH_STG; ++ch) {
      const float* wp = wbase + (size_t)(c0 + ch) * FT;  // uniform -> s_load
      const float* fp = &sfeat[ch * (PH * PW) + py * PW + px];
      #pragma unroll
      for (int dy = 0; dy < 4; ++dy) {
        const float* row = fp + dy * PW;
        float2 ra = *(const float2*)(row);      // px even, 22 even -> aligned
        float2 rb = *(const float2*)(row + 2);
        float r4 = row[4];
        float w0 = wp[dy * 4 + 0], w1 = wp[dy * 4 + 1];
        float w2 = wp[dy * 4 + 2], w3 = wp[dy * 4 + 3];
        acc0 = fmaf(ra.x, w0, acc0); acc0 = fmaf(ra.y, w1, acc0);
        acc0 = fmaf(rb.x, w2, acc0); acc0 = fmaf(rb.y, w3, acc0);
        acc1 = fmaf(ra.y, w0, acc1); acc1 = fmaf(rb.x, w1, acc1);
        acc1 = fmaf(rb.y, w2, acc1); acc1 = fmaf(r4, w3, acc1);
      }
    }
    __syncthreads();
  }
  if (act) {
    float* pp = part + ((size_t)n * CSPLIT + kc) * NPIX;
    int p0 = py * OW + px;
    pp[p0] = acc0;
    if (px + 1 < OW) pp[p0 + 1] = acc1;
  }
}

// ---------------------------------------------------------------------------
// combine partials, MODE 0: scores -> mask + residuals_mapped
// ---------------------------------------------------------------------------
__global__ __launch_bounds__(384) void combine0_k(
    const float* __restrict__ part,
    const float* __restrict__ sw, const float* __restrict__ lm,
    const float* __restrict__ alo, const float* __restrict__ ahi,
    float* __restrict__ mask, float* __restrict__ rbuf)
{
  int n = blockIdx.x;
  int p = threadIdx.x;
  if (p >= NPIX) return;
  float sv = 0.f;
  #pragma unroll
  for (int k = 0; k < CSPLIT; ++k)
    sv += part[((size_t)n * CSPLIT + k) * NPIX + p];
  int idx = n * NPIX + p;
  float lo = alo[idx], hi = ahi[idx], s_w = sw[idx], l_v = lm[idx];
  float sgn = (sv > 0.f) ? 1.f : ((sv < 0.f) ? -1.f : 0.f);
  float actv = lo * fabsf(sv) + hi * sv;
  float msk = lo * sgn + hi;
  mask[idx] = msk;
  rbuf[idx] = msk * s_w * s_w * (actv - l_v);
}

// ---------------------------------------------------------------------------
// combine partials, MODE 1: scores_grad -> per-(i,s) sum of squares
// ---------------------------------------------------------------------------
__global__ __launch_bounds__(384) void combine1_k(
    const float* __restrict__ part,
    const float* __restrict__ sw, const float* __restrict__ mask,
    float* __restrict__ den_part)
{
  __shared__ float rtmp[8];
  int n = blockIdx.x;
  int p = threadIdx.x;
  float pv = 0.f;
  if (p < NPIX) {
    float sv = 0.f;
    #pragma unroll
    for (int k = 0; k < CSPLIT; ++k)
      sv += part[((size_t)n * CSPLIT + k) * NPIX + p];
    int idx = n * NPIX + p;
    float sg = sw[idx] * mask[idx] * sv;
    pv = sg * sg;
  }
  float tot = blk_reduce(pv, rtmp);
  if (threadIdx.x == 0) den_part[(n & 63) * 3 + (n >> 6)] = tot;
}

// ---------------------------------------------------------------------------
// transpose conv: weights_grad[s,c,dy,dx] = sum_{i,y,x} feat*r  (+ reg*w)
// ---------------------------------------------------------------------------
__global__ __launch_bounds__(256) void conv_tr_k(
    const float* __restrict__ feat, const float* __restrict__ r,
    const float* __restrict__ wcur, const float* __restrict__ scal,
    float* __restrict__ wg, float* __restrict__ num_part)
{
  __shared__ float rp[3 * 21 * 21];
  __shared__ float rtmp[8];
  int tid = threadIdx.x;
  int s = blockIdx.y;
  int cblk = blockIdx.x;
  int csub = tid >> 4, tap = tid & 15;
  int dy = tap >> 2, dx = tap & 3;
  int c = cblk * 16 + csub;

  for (int idx = tid; idx < 3 * 441; idx += 256) rp[idx] = 0.f;
  __syncthreads();
  for (int idx = tid; idx < 3 * NPIX; idx += 256) {
    int i = idx / NPIX, p = idx - i * NPIX;
    int y = p / OW, x = p - y * OW;
    rp[i * 441 + (y + 1) * 21 + (x + 1)] = r[(size_t)(i * S_SEQ + s) * NPIX + p];
  }
  __syncthreads();

  float acc = 0.f;
  #pragma unroll
  for (int i = 0; i < 3; ++i) {
    const float* fp = feat + (size_t)((i * S_SEQ + s) * C_CH + c) * (H_IN * W_IN);
    const float* rpi = &rp[i * 441 + (3 - dy) * 21 + (3 - dx)];
    for (int u = 0; u < H_IN; ++u) {
      const float* frow = fp + u * W_IN;
      const float* rrow = rpi + u * 21;
      #pragma unroll
      for (int v = 0; v < W_IN; v += 2) {
        float2 f2 = *(const float2*)(frow + v);
        acc = fmaf(f2.x, rrow[v], acc);
        acc = fmaf(f2.y, rrow[v + 1], acc);
      }
    }
  }
  float regv = scal[1];
  size_t widx = ((size_t)s * C_CH + c) * FT + tap;
  float w = acc + regv * wcur[widx];
  wg[widx] = w;
  float tot = blk_reduce(w * w, rtmp);
  if (tid == 0) num_part[s * 32 + cblk] = tot;
}

// ---------------------------------------------------------------------------
// update: alpha = num / clip(den + reg*num, 1e-8); w -= step*alpha*wg
// ---------------------------------------------------------------------------
__global__ __launch_bounds__(256) void update_k(
    float* __restrict__ wcur, const float* __restrict__ wg,
    const float* __restrict__ num_part, const float* __restrict__ den_part,
    const float* __restrict__ scal)
{
  int s = blockIdx.x;
  float num = 0.f;
  #pragma unroll
  for (int k = 0; k < 32; ++k) num += num_part[s * 32 + k];
  float den = den_part[s * 3 + 0] + den_part[s * 3 + 1] + den_part[s * 3 + 2];
  float regv = scal[1], step = scal[0];
  den = fmaxf(den + regv * num, 1e-8f);
  float sa = step * (num / den);
  for (int idx = threadIdx.x; idx < C_CH * FT; idx += 256) {
    size_t g = (size_t)s * (C_CH * FT) + idx;
    wcur[g] -= sa * wg[g];
  }
}

// ---------------------------------------------------------------------------
extern "C" void kernel_launch(void* const* d_in, const int* in_sizes, int n_in,
                              void* d_out, int out_size, void* d_ws, size_t ws_size,
                              hipStream_t stream)
{
  const float* w_in = (const float*)d_in[0];
  const float* feat = (const float*)d_in[1];
  const float* bb   = (const float*)d_in[2];
  const float* lblw = (const float*)d_in[3];
  const float* mskw = (const float*)d_in[4];
  const float* spw  = (const float*)d_in[5];
  const float* lsl  = (const float*)d_in[6];
  const float* freg = (const float*)d_in[7];

  float* base = (float*)d_ws;
  const int NMAP = I_IMG * S_SEQ * NPIX;   // 69312
  const int NW   = S_SEQ * C_CH * FT;      // 524288
  float* sw   = base;
  float* lm   = sw + NMAP;
  float* alo  = lm + NMAP;
  float* ahi  = alo + NMAP;
  float* mask = ahi + NMAP;
  float* rbuf = mask + NMAP;
  float* wcur = rbuf + NMAP;
  float* wg   = wcur + NW;
  float* nump = wg + NW;
  float* denp = nump + S_SEQ * 32;
  float* scal = denp + S_SEQ * 3;
  float* partb = scal + 8;                 // I*S*CSPLIT*NPIX = 554496

  prep_k<<<I_IMG * S_SEQ, 384, 0, stream>>>(bb, lblw, mskw, spw, lsl, freg,
                                            sw, lm, alo, ahi, scal);
  hipMemcpyAsync(wcur, w_in, (size_t)NW * sizeof(float),
                 hipMemcpyDeviceToDevice, stream);

  for (int it = 0; it < NITER; ++it) {
    conv_fwd_part_k<<<dim3(I_IMG * S_SEQ, CSPLIT), 192, 0, stream>>>(
        feat, wcur, partb);
    combine0_k<<<I_IMG * S_SEQ, 384, 0, stream>>>(
        partb, sw, lm, alo, ahi, mask, rbuf);
    conv_tr_k<<<dim3(32, S_SEQ), 256, 0, stream>>>(
        feat, rbuf, wcur, scal, wg, nump);
    conv_fwd_part_k<<<dim3(I_IMG * S_SEQ, CSPLIT), 192, 0, stream>>>(
        feat, wg, partb);
    combine1_k<<<I_IMG * S_SEQ, 384, 0, stream>>>(
        partb, sw, mask, denp);
    update_k<<<S_SEQ, 256, 0, stream>>>(wcur, wg, nump, denp, scal);
  }
  hipMemcpyAsync(d_out, wcur, (size_t)NW * sizeof(float),
                 hipMemcpyDeviceToDevice, stream);
}

// Round 3
// 814.770 us; speedup vs baseline: 4.6216x; 1.3279x over previous
//
#include <hip/hip_runtime.h>
#include <math.h>

#define I_IMG 3
#define S_SEQ 64
#define C_CH  512
#define H_IN  18
#define W_IN  18
#define OH 19
#define OW 19
#define NPIX 361
#define FT 16
#define NITER 5
#define CH_STG 8
#define CSPLIT 8
#define CPB 64      // channels per conv_fwd block
#define PLW 28      // padded LDS row stride (mod 32 = 28 -> 8-cycle bank bases)
#define PLH 22
#define PLANE (PLH * PLW)   // 616 floats

__device__ inline float blk_reduce(float v, float* tmp) {
  #pragma unroll
  for (int o = 32; o > 0; o >>= 1) v += __shfl_down(v, o, 64);
  int lane = threadIdx.x & 63;
  int w = threadIdx.x >> 6;
  if (lane == 0) tmp[w] = v;
  __syncthreads();
  float r = 0.f;
  if (threadIdx.x == 0) {
    int nw = (blockDim.x + 63) >> 6;
    for (int k = 0; k < nw; ++k) r += tmp[k];
  }
  return r;
}

// ---------------------------------------------------------------------------
// prep: distance map -> label_map, sample_weight, a_lo, a_hi; scalars
// ---------------------------------------------------------------------------
__global__ void prep_k(const float* __restrict__ bb,
                       const float* __restrict__ label_w,
                       const float* __restrict__ mask_w,
                       const float* __restrict__ spatial_w,
                       const float* __restrict__ lsl,
                       const float* __restrict__ freg,
                       float* __restrict__ sw, float* __restrict__ lm,
                       float* __restrict__ alo, float* __restrict__ ahi,
                       float* __restrict__ scal)
{
  int n = blockIdx.x;     // n = i*S + s
  int p = threadIdx.x;
  if (n == 0 && p == 0) {
    scal[0] = expf(lsl[0]);                    // step
    scal[1] = fmaxf(freg[0] * freg[0], 1e-6f); // reg
  }
  if (p >= NPIX) return;
  float bx = bb[n * 4 + 0], by = bb[n * 4 + 1];
  float bw = bb[n * 4 + 2], bh = bb[n * 4 + 3];
  float crow = (by + bh * 0.5f) * (1.f / 16.f);
  float ccol = (bx + bw * 0.5f) * (1.f / 16.f);
  int y = p / OW, x = p - (p / OW) * OW;
  float d0 = (float)y - crow, d1 = (float)x - ccol;
  float dist = sqrtf(d0 * d0 + d1 * d1);
  float bins[5];
  #pragma unroll
  for (int b = 0; b < 4; ++b) bins[b] = fmaxf(1.f - fabsf(dist - (float)b), 0.f);
  bins[4] = fminf(fmaxf(dist - 3.f, 0.f), 1.f);
  float lmv = 0.f, mm = 0.f, sp = 0.f;
  #pragma unroll
  for (int b = 0; b < 5; ++b) {
    lmv += bins[b] * label_w[b];
    mm  += bins[b] * mask_w[b];
    sp  += bins[b] * spatial_w[b];
  }
  float tm = 1.f / (1.f + expf(-mm));
  int idx = n * NPIX + p;
  lm[idx]  = lmv;
  sw[idx]  = 0.57735026918962584f * sp;   // sqrt(1/3) * spatial_weight
  alo[idx] = 0.5f * (1.f - tm);
  ahi[idx] = 0.5f * (1.f + tm);
}

// ---------------------------------------------------------------------------
// forward grouped conv, channel-split partials.
// grid (I*S, CSPLIT), block 192 = 3 waves.
// Thread = 4-px horizontal strip, lane pair = 2 channels in flight.
// All feat reads are aligned ds_read_b128 from a 22x28 padded plane.
// ---------------------------------------------------------------------------
__global__ __launch_bounds__(192) void conv_fwd_part_k(
    const float* __restrict__ feat, const float* __restrict__ wsrc,
    float* __restrict__ part)
{
  __shared__ __align__(16) float sfeat[CH_STG * PLANE];
  int tid = threadIdx.x;
  int n = blockIdx.x;
  int s = n & 63;
  int kc = blockIdx.y;
  const float* fbase = feat + ((size_t)n * C_CH + kc * CPB) * (H_IN * W_IN);
  const float* wbase = wsrc + ((size_t)s * C_CH + kc * CPB) * FT;

  // zero whole buffer once (pads stay zero forever)
  for (int idx = tid; idx < CH_STG * PLANE; idx += 192) sfeat[idx] = 0.f;

  // staging map: one 18-float input row per thread (t < 144)
  int ch_l = tid / 18;
  int row_l = tid - ch_l * 18;
  bool stager = tid < 144;

  // compute map: pos -> (row, strip), chsub = low bit (pairs share a strip)
  int pos = tid >> 1;
  int chsub = tid & 1;
  bool act = pos < 95;
  int rowq = act ? (pos / 5) : 0;
  int strip = act ? (pos - (pos / 5) * 5) : 0;

  float acc0 = 0.f, acc1 = 0.f, acc2 = 0.f, acc3 = 0.f;
  __syncthreads();

  for (int c0 = 0; c0 < CPB; c0 += CH_STG) {
    if (stager) {
      const float* src = fbase + (size_t)(c0 + ch_l) * (H_IN * W_IN) + row_l * W_IN;
      float* dst = &sfeat[ch_l * PLANE + (row_l + 2) * PLW + 2];
      #pragma unroll
      for (int k = 0; k < 9; ++k) {
        float2 v = *(const float2*)(src + 2 * k);
        *(float2*)(dst + 2 * k) = v;
      }
    }
    __syncthreads();

    #pragma unroll
    for (int i = 0; i < 4; ++i) {
      int ch = 2 * i + chsub;
      const float4* wp = (const float4*)(wbase + (size_t)(c0 + ch) * FT);
      float4 wr0 = wp[0], wr1 = wp[1], wr2 = wp[2], wr3 = wp[3];
      const float* plane = &sfeat[ch * PLANE + rowq * PLW + strip * 4];
      #pragma unroll
      for (int dy = 0; dy < 4; ++dy) {
        float4 wr = (dy == 0) ? wr0 : (dy == 1) ? wr1 : (dy == 2) ? wr2 : wr3;
        float4 ra = *(const float4*)(plane + dy * PLW);
        float4 rb = *(const float4*)(plane + dy * PLW + 4);
        acc0 = fmaf(ra.x, wr.x, acc0); acc0 = fmaf(ra.y, wr.y, acc0);
        acc0 = fmaf(ra.z, wr.z, acc0); acc0 = fmaf(ra.w, wr.w, acc0);
        acc1 = fmaf(ra.y, wr.x, acc1); acc1 = fmaf(ra.z, wr.y, acc1);
        acc1 = fmaf(ra.w, wr.z, acc1); acc1 = fmaf(rb.x, wr.w, acc1);
        acc2 = fmaf(ra.z, wr.x, acc2); acc2 = fmaf(ra.w, wr.y, acc2);
        acc2 = fmaf(rb.x, wr.z, acc2); acc2 = fmaf(rb.y, wr.w, acc2);
        acc3 = fmaf(ra.w, wr.x, acc3); acc3 = fmaf(rb.x, wr.y, acc3);
        acc3 = fmaf(rb.y, wr.z, acc3); acc3 = fmaf(rb.z, wr.w, acc3);
      }
    }
    __syncthreads();
  }

  // combine channel pair: lane^1 holds the other channel's partial
  acc0 += __shfl_xor(acc0, 1, 64);
  acc1 += __shfl_xor(acc1, 1, 64);
  acc2 += __shfl_xor(acc2, 1, 64);
  acc3 += __shfl_xor(acc3, 1, 64);

  if (act) {
    float* pp = part + ((size_t)n * CSPLIT + kc) * NPIX + rowq * OW;
    int cbase = strip * 4 + 2 * chsub;
    float v0 = chsub ? acc2 : acc0;
    float v1 = chsub ? acc3 : acc1;
    if (cbase < OW) pp[cbase] = v0;
    if (cbase + 1 < OW) pp[cbase + 1] = v1;
  }
}

// ---------------------------------------------------------------------------
// combine partials, MODE 0: scores -> mask + residuals_mapped
// ---------------------------------------------------------------------------
__global__ __launch_bounds__(384) void combine0_k(
    const float* __restrict__ part,
    const float* __restrict__ sw, const float* __restrict__ lm,
    const float* __restrict__ alo, const float* __restrict__ ahi,
    float* __restrict__ mask, float* __restrict__ rbuf)
{
  int n = blockIdx.x;
  int p = threadIdx.x;
  if (p >= NPIX) return;
  float sv = 0.f;
  #pragma unroll
  for (int k = 0; k < CSPLIT; ++k)
    sv += part[((size_t)n * CSPLIT + k) * NPIX + p];
  int idx = n * NPIX + p;
  float lo = alo[idx], hi = ahi[idx], s_w = sw[idx], l_v = lm[idx];
  float sgn = (sv > 0.f) ? 1.f : ((sv < 0.f) ? -1.f : 0.f);
  float actv = lo * fabsf(sv) + hi * sv;
  float msk = lo * sgn + hi;
  mask[idx] = msk;
  rbuf[idx] = msk * s_w * s_w * (actv - l_v);
}

// ---------------------------------------------------------------------------
// combine partials, MODE 1: scores_grad -> per-(i,s) sum of squares
// ---------------------------------------------------------------------------
__global__ __launch_bounds__(384) void combine1_k(
    const float* __restrict__ part,
    const float* __restrict__ sw, const float* __restrict__ mask,
    float* __restrict__ den_part)
{
  __shared__ float rtmp[8];
  int n = blockIdx.x;
  int p = threadIdx.x;
  float pv = 0.f;
  if (p < NPIX) {
    float sv = 0.f;
    #pragma unroll
    for (int k = 0; k < CSPLIT; ++k)
      sv += part[((size_t)n * CSPLIT + k) * NPIX + p];
    int idx = n * NPIX + p;
    float sg = sw[idx] * mask[idx] * sv;
    pv = sg * sg;
  }
  float tot = blk_reduce(pv, rtmp);
  if (threadIdx.x == 0) den_part[(n & 63) * 3 + (n >> 6)] = tot;
}

// ---------------------------------------------------------------------------
// transpose conv: weights_grad[s,c,dy,dx] = sum_{i,y,x} feat*r  (+ reg*w)
// ---------------------------------------------------------------------------
__global__ __launch_bounds__(256) void conv_tr_k(
    const float* __restrict__ feat, const float* __restrict__ r,
    const float* __restrict__ wcur, const float* __restrict__ scal,
    float* __restrict__ wg, float* __restrict__ num_part)
{
  __shared__ float rp[3 * 21 * 21];
  __shared__ float rtmp[8];
  int tid = threadIdx.x;
  int s = blockIdx.y;
  int cblk = blockIdx.x;
  int csub = tid >> 4, tap = tid & 15;
  int dy = tap >> 2, dx = tap & 3;
  int c = cblk * 16 + csub;

  for (int idx = tid; idx < 3 * 441; idx += 256) rp[idx] = 0.f;
  __syncthreads();
  for (int idx = tid; idx < 3 * NPIX; idx += 256) {
    int i = idx / NPIX, p = idx - i * NPIX;
    int y = p / OW, x = p - y * OW;
    rp[i * 441 + (y + 1) * 21 + (x + 1)] = r[(size_t)(i * S_SEQ + s) * NPIX + p];
  }
  __syncthreads();

  float acc = 0.f;
  #pragma unroll
  for (int i = 0; i < 3; ++i) {
    const float* fp = feat + (size_t)((i * S_SEQ + s) * C_CH + c) * (H_IN * W_IN);
    const float* rpi = &rp[i * 441 + (3 - dy) * 21 + (3 - dx)];
    for (int u = 0; u < H_IN; ++u) {
      const float* frow = fp + u * W_IN;
      const float* rrow = rpi + u * 21;
      #pragma unroll
      for (int v = 0; v < W_IN; v += 2) {
        float2 f2 = *(const float2*)(frow + v);
        acc = fmaf(f2.x, rrow[v], acc);
        acc = fmaf(f2.y, rrow[v + 1], acc);
      }
    }
  }
  float regv = scal[1];
  size_t widx = ((size_t)s * C_CH + c) * FT + tap;
  float w = acc + regv * wcur[widx];
  wg[widx] = w;
  float tot = blk_reduce(w * w, rtmp);
  if (tid == 0) num_part[s * 32 + cblk] = tot;
}

// ---------------------------------------------------------------------------
// update: alpha = num / clip(den + reg*num, 1e-8); w -= step*alpha*wg
// ---------------------------------------------------------------------------
__global__ __launch_bounds__(256) void update_k(
    float* __restrict__ wcur, const float* __restrict__ wg,
    const float* __restrict__ num_part, const float* __restrict__ den_part,
    const float* __restrict__ scal)
{
  int s = blockIdx.x;
  float num = 0.f;
  #pragma unroll
  for (int k = 0; k < 32; ++k) num += num_part[s * 32 + k];
  float den = den_part[s * 3 + 0] + den_part[s * 3 + 1] + den_part[s * 3 + 2];
  float regv = scal[1], step = scal[0];
  den = fmaxf(den + regv * num, 1e-8f);
  float sa = step * (num / den);
  for (int idx = threadIdx.x; idx < C_CH * FT; idx += 256) {
    size_t g = (size_t)s * (C_CH * FT) + idx;
    wcur[g] -= sa * wg[g];
  }
}

// ---------------------------------------------------------------------------
extern "C" void kernel_launch(void* const* d_in, const int* in_sizes, int n_in,
                              void* d_out, int out_size, void* d_ws, size_t ws_size,
                              hipStream_t stream)
{
  const float* w_in = (const float*)d_in[0];
  const float* feat = (const float*)d_in[1];
  const float* bb   = (const float*)d_in[2];
  const float* lblw = (const float*)d_in[3];
  const float* mskw = (const float*)d_in[4];
  const float* spw  = (const float*)d_in[5];
  const float* lsl  = (const float*)d_in[6];
  const float* freg = (const float*)d_in[7];

  float* base = (float*)d_ws;
  const int NMAP = I_IMG * S_SEQ * NPIX;   // 69312
  const int NW   = S_SEQ * C_CH * FT;      // 524288
  float* sw   = base;
  float* lm   = sw + NMAP;
  float* alo  = lm + NMAP;
  float* ahi  = alo + NMAP;
  float* mask = ahi + NMAP;
  float* rbuf = mask + NMAP;
  float* wcur = rbuf + NMAP;
  float* wg   = wcur + NW;
  float* nump = wg + NW;
  float* denp = nump + S_SEQ * 32;
  float* scal = denp + S_SEQ * 3;
  float* partb = scal + 8;                 // I*S*CSPLIT*NPIX = 554496

  prep_k<<<I_IMG * S_SEQ, 384, 0, stream>>>(bb, lblw, mskw, spw, lsl, freg,
                                            sw, lm, alo, ahi, scal);
  hipMemcpyAsync(wcur, w_in, (size_t)NW * sizeof(float),
                 hipMemcpyDeviceToDevice, stream);

  for (int it = 0; it < NITER; ++it) {
    conv_fwd_part_k<<<dim3(I_IMG * S_SEQ, CSPLIT), 192, 0, stream>>>(
        feat, wcur, partb);
    combine0_k<<<I_IMG * S_SEQ, 384, 0, stream>>>(
        partb, sw, lm, alo, ahi, mask, rbuf);
    conv_tr_k<<<dim3(32, S_SEQ), 256, 0, stream>>>(
        feat, rbuf, wcur, scal, wg, nump);
    conv_fwd_part_k<<<dim3(I_IMG * S_SEQ, CSPLIT), 192, 0, stream>>>(
        feat, wg, partb);
    combine1_k<<<I_IMG * S_SEQ, 384, 0, stream>>>(
        partb, sw, mask, denp);
    update_k<<<S_SEQ, 256, 0, stream>>>(wcur, wg, nump, denp, scal);
  }
  hipMemcpyAsync(d_out, wcur, (size_t)NW * sizeof(float),
                 hipMemcpyDeviceToDevice, stream);
}

// Round 4
// 731.827 us; speedup vs baseline: 5.1454x; 1.1133x over previous
//
#include <hip/hip_runtime.h>
#include <math.h>

#define I_IMG 3
#define S_SEQ 64
#define C_CH  512
#define H_IN  18
#define W_IN  18
#define OH 19
#define OW 19
#define NPIX 361
#define PPIX 400          // padded 20x20 partial plane
#define FT 16
#define NITER 5
#define CSPLIT 8
#define CPB 64            // channels per conv_fwd block
#define PLW 24            // fwd LDS plane row stride (floats)
#define PLSZ 580          // fwd LDS plane stride (24 rows x 24 + 4 pad -> slot banks 4s)
#define RPW 24            // tr rp row stride
#define RPSZ 504          // 21 rows x 24

__device__ inline float blk_reduce(float v, float* tmp) {
  #pragma unroll
  for (int o = 32; o > 0; o >>= 1) v += __shfl_down(v, o, 64);
  int lane = threadIdx.x & 63;
  int w = threadIdx.x >> 6;
  if (lane == 0) tmp[w] = v;
  __syncthreads();
  float r = 0.f;
  if (threadIdx.x == 0) {
    int nw = (blockDim.x + 63) >> 6;
    for (int k = 0; k < nw; ++k) r += tmp[k];
  }
  return r;
}

// ---------------------------------------------------------------------------
// prep: distance map -> label_map, sample_weight, a_lo, a_hi; scalars
// ---------------------------------------------------------------------------
__global__ void prep_k(const float* __restrict__ bb,
                       const float* __restrict__ label_w,
                       const float* __restrict__ mask_w,
                       const float* __restrict__ spatial_w,
                       const float* __restrict__ lsl,
                       const float* __restrict__ freg,
                       float* __restrict__ sw, float* __restrict__ lm,
                       float* __restrict__ alo, float* __restrict__ ahi,
                       float* __restrict__ scal)
{
  int n = blockIdx.x;     // n = i*S + s
  int p = threadIdx.x;
  if (n == 0 && p == 0) {
    scal[0] = expf(lsl[0]);                    // step
    scal[1] = fmaxf(freg[0] * freg[0], 1e-6f); // reg
  }
  if (p >= NPIX) return;
  float bx = bb[n * 4 + 0], by = bb[n * 4 + 1];
  float bw = bb[n * 4 + 2], bh = bb[n * 4 + 3];
  float crow = (by + bh * 0.5f) * (1.f / 16.f);
  float ccol = (bx + bw * 0.5f) * (1.f / 16.f);
  int y = p / OW, x = p - (p / OW) * OW;
  float d0 = (float)y - crow, d1 = (float)x - ccol;
  float dist = sqrtf(d0 * d0 + d1 * d1);
  float bins[5];
  #pragma unroll
  for (int b = 0; b < 4; ++b) bins[b] = fmaxf(1.f - fabsf(dist - (float)b), 0.f);
  bins[4] = fminf(fmaxf(dist - 3.f, 0.f), 1.f);
  float lmv = 0.f, mm = 0.f, sp = 0.f;
  #pragma unroll
  for (int b = 0; b < 5; ++b) {
    lmv += bins[b] * label_w[b];
    mm  += bins[b] * mask_w[b];
    sp  += bins[b] * spatial_w[b];
  }
  float tm = 1.f / (1.f + expf(-mm));
  int idx = n * NPIX + p;
  lm[idx]  = lmv;
  sw[idx]  = 0.57735026918962584f * sp;   // sqrt(1/3) * spatial_weight
  alo[idx] = 0.5f * (1.f - tm);
  ahi[idx] = 0.5f * (1.f + tm);
}

// ---------------------------------------------------------------------------
// forward grouped conv, channel-split partials.
// grid (I*S, CSPLIT), block 192. tid = pos*8 + slot.
// pos<20: ty=pos/5 (5-row tile), tx=pos%5 (4-col tile). slot = channel lane.
// Per channel: 16 ds_read_b128 -> 320 FMA. Cross-slot reduce via shfl_xor.
// ---------------------------------------------------------------------------
__global__ __launch_bounds__(192) void conv_fwd_part_k(
    const float* __restrict__ feat, const float* __restrict__ wsrc,
    float* __restrict__ part)
{
  __shared__ __align__(16) float sfeat[8 * PLSZ];
  int tid = threadIdx.x;
  int n = blockIdx.x;
  int s = n & 63;
  int kc = blockIdx.y;
  const float* fbase = feat + ((size_t)n * C_CH + kc * CPB) * (H_IN * W_IN);
  const float* wbase = wsrc + ((size_t)s * C_CH + kc * CPB) * FT;

  for (int idx = tid; idx < 8 * PLSZ; idx += 192) sfeat[idx] = 0.f;

  // staging map: ch = tid/24, row r = tid%24 (active r<18)
  int ch_l = tid / 24;
  int row_l = tid - ch_l * 24;
  bool stager = row_l < 18;

  int pos = tid >> 3;
  int slot = tid & 7;
  bool act = pos < 20;
  int cpos = act ? pos : 19;
  int ty = cpos / 5, tx = cpos - (cpos / 5) * 5;

  float acc[5][4];
  #pragma unroll
  for (int r = 0; r < 5; ++r)
    #pragma unroll
    for (int c = 0; c < 4; ++c) acc[r][c] = 0.f;

  const float* plane0 = &sfeat[slot * PLSZ + (5 * ty) * PLW + 4 * tx];
  __syncthreads();

  for (int c0 = 0; c0 < CPB; c0 += 8) {
    if (stager) {
      const float* src = fbase + (size_t)(c0 + ch_l) * (H_IN * W_IN) + row_l * W_IN;
      float* dst = &sfeat[ch_l * PLSZ + (row_l + 2) * PLW + 2];
      #pragma unroll
      for (int k = 0; k < 9; ++k) {
        float2 v = *(const float2*)(src + 2 * k);
        *(float2*)(dst + 2 * k) = v;
      }
    }
    __syncthreads();

    const float4* wp = (const float4*)(wbase + (size_t)(c0 + slot) * FT);
    float4 w0 = wp[0], w1 = wp[1], w2 = wp[2], w3 = wp[3];

    #pragma unroll
    for (int ri = 0; ri < 8; ++ri) {
      float4 ra = *(const float4*)(plane0 + ri * PLW);
      float4 rb = *(const float4*)(plane0 + ri * PLW + 4);
      #pragma unroll
      for (int dy = 0; dy < 4; ++dy) {
        int r = ri - dy;
        if (r < 0 || r > 4) continue;
        float4 wr = (dy == 0) ? w0 : (dy == 1) ? w1 : (dy == 2) ? w2 : w3;
        acc[r][0] = fmaf(ra.x, wr.x, acc[r][0]); acc[r][0] = fmaf(ra.y, wr.y, acc[r][0]);
        acc[r][0] = fmaf(ra.z, wr.z, acc[r][0]); acc[r][0] = fmaf(ra.w, wr.w, acc[r][0]);
        acc[r][1] = fmaf(ra.y, wr.x, acc[r][1]); acc[r][1] = fmaf(ra.z, wr.y, acc[r][1]);
        acc[r][1] = fmaf(ra.w, wr.z, acc[r][1]); acc[r][1] = fmaf(rb.x, wr.w, acc[r][1]);
        acc[r][2] = fmaf(ra.z, wr.x, acc[r][2]); acc[r][2] = fmaf(ra.w, wr.y, acc[r][2]);
        acc[r][2] = fmaf(rb.x, wr.z, acc[r][2]); acc[r][2] = fmaf(rb.y, wr.w, acc[r][2]);
        acc[r][3] = fmaf(ra.w, wr.x, acc[r][3]); acc[r][3] = fmaf(rb.x, wr.y, acc[r][3]);
        acc[r][3] = fmaf(rb.y, wr.z, acc[r][3]); acc[r][3] = fmaf(rb.z, wr.w, acc[r][3]);
      }
    }
    __syncthreads();
  }

  // reduce across the 8 channel slots (lanes pos*8 .. pos*8+7, same wave)
  #pragma unroll
  for (int r = 0; r < 5; ++r)
    #pragma unroll
    for (int c = 0; c < 4; ++c) {
      float v = acc[r][c];
      v += __shfl_xor(v, 1, 64);
      v += __shfl_xor(v, 2, 64);
      v += __shfl_xor(v, 4, 64);
      acc[r][c] = v;
    }

  // slot r (<5) stores output row 5ty+r, cols 4tx..4tx+3
  int orow = 5 * ty + slot;
  if (act && slot < 5 && orow < OH) {
    float4 v = make_float4(acc[slot][0], acc[slot][1], acc[slot][2], acc[slot][3]);
    *(float4*)(part + ((size_t)n * CSPLIT + kc) * PPIX + orow * 20 + 4 * tx) = v;
  }
}

// ---------------------------------------------------------------------------
// combine partials: scores -> mask + residuals_mapped
// ---------------------------------------------------------------------------
__global__ __launch_bounds__(384) void combine0_k(
    const float* __restrict__ part,
    const float* __restrict__ sw, const float* __restrict__ lm,
    const float* __restrict__ alo, const float* __restrict__ ahi,
    float* __restrict__ mask, float* __restrict__ rbuf)
{
  int n = blockIdx.x;
  int p = threadIdx.x;
  if (p >= NPIX) return;
  int y = p / OW, x = p - y * OW;
  const float* pb = part + (size_t)n * CSPLIT * PPIX + y * 20 + x;
  float sv = 0.f;
  #pragma unroll
  for (int k = 0; k < CSPLIT; ++k) sv += pb[k * PPIX];
  int idx = n * NPIX + p;
  float lo = alo[idx], hi = ahi[idx], s_w = sw[idx], l_v = lm[idx];
  float sgn = (sv > 0.f) ? 1.f : ((sv < 0.f) ? -1.f : 0.f);
  float actv = lo * fabsf(sv) + hi * sv;
  float msk = lo * sgn + hi;
  mask[idx] = msk;
  rbuf[idx] = msk * s_w * s_w * (actv - l_v);
}

// ---------------------------------------------------------------------------
// transpose conv: wg[s,c,dy,dx] = sum_{i,u,v} feat[i,s,c,u,v]*rp_i[u+3-dy,v+3-dx]
// grid (8 cblk, 64 s), block 192 = 3 waves; wave = image i, lane = channel.
// rp reads are wave-uniform -> LDS broadcast (conflict-free).
// ---------------------------------------------------------------------------
__global__ __launch_bounds__(192) void conv_tr_k(
    const float* __restrict__ feat, const float* __restrict__ r,
    const float* __restrict__ wcur, const float* __restrict__ scal,
    float* __restrict__ wg, float* __restrict__ num_part)
{
  __shared__ __align__(16) float rp[3 * RPSZ];
  __shared__ float swg[3 * 64 * FT];
  __shared__ float rtmp[3];
  int tid = threadIdx.x;
  int s = blockIdx.y;
  int cblk = blockIdx.x;
  int i = tid >> 6;        // wave = image
  int cl = tid & 63;       // lane = channel within block
  int c = cblk * 64 + cl;

  for (int idx = tid; idx < 3 * RPSZ; idx += 192) rp[idx] = 0.f;
  __syncthreads();
  for (int idx = tid; idx < 3 * NPIX; idx += 192) {
    int ii = idx / NPIX, p = idx - ii * NPIX;
    int y = p / OW, x = p - y * OW;
    rp[ii * RPSZ + (y + 1) * RPW + (x + 1)] = r[(size_t)(ii * S_SEQ + s) * NPIX + p];
  }
  __syncthreads();

  const float* plane = &rp[i * RPSZ];
  const float* fpl = feat + (size_t)((i * S_SEQ + s) * C_CH + c) * (H_IN * W_IN);

  float acc[FT];
  #pragma unroll
  for (int t = 0; t < FT; ++t) acc[t] = 0.f;

  for (int u = 0; u < H_IN; ++u) {
    const float* frow = fpl + u * W_IN;
    const float* prow = plane + (u + 3) * RPW;   // row for dy=0; dy -> -dy*RPW
    // strips v0 = 0, 8 (full 8 cols)
    #pragma unroll
    for (int st = 0; st < 2; ++st) {
      int v0 = st * 8;
      float f[8];
      #pragma unroll
      for (int k = 0; k < 4; ++k) {
        float2 v = *(const float2*)(frow + v0 + 2 * k);
        f[2 * k] = v.x; f[2 * k + 1] = v.y;
      }
      #pragma unroll
      for (int dy = 0; dy < 4; ++dy) {
        const float* rr = prow - dy * RPW + v0;
        float4 s0 = *(const float4*)(rr);
        float4 s1 = *(const float4*)(rr + 4);
        float4 s2 = *(const float4*)(rr + 8);
        float seg[12] = {s0.x, s0.y, s0.z, s0.w, s1.x, s1.y, s1.z, s1.w,
                         s2.x, s2.y, s2.z, s2.w};
        #pragma unroll
        for (int dx = 0; dx < 4; ++dx) {
          float a = acc[dy * 4 + dx];
          #pragma unroll
          for (int j = 0; j < 8; ++j) a = fmaf(f[j], seg[j + 3 - dx], a);
          acc[dy * 4 + dx] = a;
        }
      }
    }
    // tail strip v = 16,17
    {
      float2 ft = *(const float2*)(frow + 16);
      #pragma unroll
      for (int dy = 0; dy < 4; ++dy) {
        const float* rr = prow - dy * RPW + 16;
        float4 s0 = *(const float4*)(rr);
        float4 s1 = *(const float4*)(rr + 4);
        float seg[8] = {s0.x, s0.y, s0.z, s0.w, s1.x, s1.y, s1.z, s1.w};
        #pragma unroll
        for (int dx = 0; dx < 4; ++dx) {
          float a = acc[dy * 4 + dx];
          a = fmaf(ft.x, seg[3 - dx], a);
          a = fmaf(ft.y, seg[4 - dx], a);
          acc[dy * 4 + dx] = a;
        }
      }
    }
  }

  // reduce across images via LDS, add reg term, write wg + alpha_num partial
  #pragma unroll
  for (int t = 0; t < FT; ++t) swg[(i * 64 + cl) * FT + t] = acc[t];
  __syncthreads();

  float regv = scal[1];
  float sq = 0.f;
  for (int g = tid; g < 64 * FT; g += 192) {
    int cc = g >> 4, t = g & 15;
    float v = swg[cc * FT + t] + swg[(64 + cc) * FT + t] + swg[(128 + cc) * FT + t];
    size_t widx = ((size_t)s * C_CH + cblk * 64 + cc) * FT + t;
    v += regv * wcur[widx];
    wg[widx] = v;
    sq += v * v;
  }
  float tot = blk_reduce(sq, rtmp);
  if (tid == 0) num_part[s * 8 + cblk] = tot;
}

// ---------------------------------------------------------------------------
// update (merged combine1): den from scores_grad partials, then weight step
// ---------------------------------------------------------------------------
__global__ __launch_bounds__(256) void update_k(
    float* __restrict__ wcur, const float* __restrict__ wg,
    const float* __restrict__ partb,
    const float* __restrict__ sw, const float* __restrict__ mask,
    const float* __restrict__ num_part, const float* __restrict__ scal)
{
  __shared__ float rtmp[4];
  __shared__ float s_sa;
  int s = blockIdx.x;
  int tid = threadIdx.x;

  float sq = 0.f;
  for (int g = tid; g < I_IMG * NPIX; g += 256) {
    int i = g / NPIX, p = g - i * NPIX;
    int n = i * S_SEQ + s;
    int y = p / OW, x = p - y * OW;
    const float* pb = partb + (size_t)n * CSPLIT * PPIX + y * 20 + x;
    float sv = 0.f;
    #pragma unroll
    for (int k = 0; k < CSPLIT; ++k) sv += pb[k * PPIX];
    int idx = n * NPIX + p;
    float sg = sw[idx] * mask[idx] * sv;
    sq += sg * sg;
  }
  float den = blk_reduce(sq, rtmp);
  if (tid == 0) {
    float num = 0.f;
    #pragma unroll
    for (int k = 0; k < 8; ++k) num += num_part[s * 8 + k];
    float regv = scal[1], step = scal[0];
    float d = fmaxf(den + regv * num, 1e-8f);
    s_sa = step * (num / d);
  }
  __syncthreads();
  float sa = s_sa;
  float4* w4 = (float4*)(wcur + (size_t)s * (C_CH * FT));
  const float4* g4 = (const float4*)(wg + (size_t)s * (C_CH * FT));
  for (int idx = tid; idx < C_CH * FT / 4; idx += 256) {
    float4 w = w4[idx], g = g4[idx];
    w.x -= sa * g.x; w.y -= sa * g.y; w.z -= sa * g.z; w.w -= sa * g.w;
    w4[idx] = w;
  }
}

// ---------------------------------------------------------------------------
extern "C" void kernel_launch(void* const* d_in, const int* in_sizes, int n_in,
                              void* d_out, int out_size, void* d_ws, size_t ws_size,
                              hipStream_t stream)
{
  const float* w_in = (const float*)d_in[0];
  const float* feat = (const float*)d_in[1];
  const float* bb   = (const float*)d_in[2];
  const float* lblw = (const float*)d_in[3];
  const float* mskw = (const float*)d_in[4];
  const float* spw  = (const float*)d_in[5];
  const float* lsl  = (const float*)d_in[6];
  const float* freg = (const float*)d_in[7];

  float* base = (float*)d_ws;
  const int NMAP = I_IMG * S_SEQ * NPIX;   // 69312
  const int NW   = S_SEQ * C_CH * FT;      // 524288
  float* sw   = base;
  float* lm   = sw + NMAP;
  float* alo  = lm + NMAP;
  float* ahi  = alo + NMAP;
  float* mask = ahi + NMAP;
  float* rbuf = mask + NMAP;
  float* wcur = rbuf + NMAP;
  float* wg   = wcur + NW;
  float* nump = wg + NW;
  float* scal = nump + S_SEQ * 8;
  float* partb = scal + 8;                 // I*S*CSPLIT*PPIX = 614400

  prep_k<<<I_IMG * S_SEQ, 384, 0, stream>>>(bb, lblw, mskw, spw, lsl, freg,
                                            sw, lm, alo, ahi, scal);
  hipMemcpyAsync(wcur, w_in, (size_t)NW * sizeof(float),
                 hipMemcpyDeviceToDevice, stream);

  for (int it = 0; it < NITER; ++it) {
    conv_fwd_part_k<<<dim3(I_IMG * S_SEQ, CSPLIT), 192, 0, stream>>>(
        feat, wcur, partb);
    combine0_k<<<I_IMG * S_SEQ, 384, 0, stream>>>(
        partb, sw, lm, alo, ahi, mask, rbuf);
    conv_tr_k<<<dim3(8, S_SEQ), 192, 0, stream>>>(
        feat, rbuf, wcur, scal, wg, nump);
    conv_fwd_part_k<<<dim3(I_IMG * S_SEQ, CSPLIT), 192, 0, stream>>>(
        feat, wg, partb);
    update_k<<<S_SEQ, 256, 0, stream>>>(
        wcur, wg, partb, sw, mask, nump, scal);
  }
  hipMemcpyAsync(d_out, wcur, (size_t)NW * sizeof(float),
                 hipMemcpyDeviceToDevice, stream);
}

// Round 5
// 560.898 us; speedup vs baseline: 6.7134x; 1.3047x over previous
//
#include <hip/hip_runtime.h>
#include <math.h>

#define I_IMG 3
#define S_SEQ 64
#define C_CH  512
#define H_IN  18
#define W_IN  18
#define OH 19
#define OW 19
#define NPIX 361
#define PPIX 400          // padded 20x20 partial plane
#define FT 16
#define NITER 5
#define CSPLIT 8
#define CPB 64            // channels per conv_fwd block
#define PLW 24            // fwd LDS plane row stride (floats)
#define PLSZ 580          // fwd LDS plane stride
#define RPW 24            // tr rp row stride
#define RPSZ 504          // 21 rows x 24

__device__ inline float blk_reduce(float v, float* tmp) {
  #pragma unroll
  for (int o = 32; o > 0; o >>= 1) v += __shfl_down(v, o, 64);
  int lane = threadIdx.x & 63;
  int w = threadIdx.x >> 6;
  if (lane == 0) tmp[w] = v;
  __syncthreads();
  float r = 0.f;
  if (threadIdx.x == 0) {
    int nw = (blockDim.x + 63) >> 6;
    for (int k = 0; k < nw; ++k) r += tmp[k];
  }
  return r;
}

// ---------------------------------------------------------------------------
// prep: distance map -> label_map, sample_weight, a_lo, a_hi; scalars
// ---------------------------------------------------------------------------
__global__ void prep_k(const float* __restrict__ bb,
                       const float* __restrict__ label_w,
                       const float* __restrict__ mask_w,
                       const float* __restrict__ spatial_w,
                       const float* __restrict__ lsl,
                       const float* __restrict__ freg,
                       float* __restrict__ sw, float* __restrict__ lm,
                       float* __restrict__ alo, float* __restrict__ ahi,
                       float* __restrict__ scal)
{
  int n = blockIdx.x;     // n = i*S + s
  int p = threadIdx.x;
  if (n == 0 && p == 0) {
    scal[0] = expf(lsl[0]);                    // step
    scal[1] = fmaxf(freg[0] * freg[0], 1e-6f); // reg
  }
  if (p >= NPIX) return;
  float bx = bb[n * 4 + 0], by = bb[n * 4 + 1];
  float bw = bb[n * 4 + 2], bh = bb[n * 4 + 3];
  float crow = (by + bh * 0.5f) * (1.f / 16.f);
  float ccol = (bx + bw * 0.5f) * (1.f / 16.f);
  int y = p / OW, x = p - (p / OW) * OW;
  float d0 = (float)y - crow, d1 = (float)x - ccol;
  float dist = sqrtf(d0 * d0 + d1 * d1);
  float bins[5];
  #pragma unroll
  for (int b = 0; b < 4; ++b) bins[b] = fmaxf(1.f - fabsf(dist - (float)b), 0.f);
  bins[4] = fminf(fmaxf(dist - 3.f, 0.f), 1.f);
  float lmv = 0.f, mm = 0.f, sp = 0.f;
  #pragma unroll
  for (int b = 0; b < 5; ++b) {
    lmv += bins[b] * label_w[b];
    mm  += bins[b] * mask_w[b];
    sp  += bins[b] * spatial_w[b];
  }
  float tm = 1.f / (1.f + expf(-mm));
  int idx = n * NPIX + p;
  lm[idx]  = lmv;
  sw[idx]  = 0.57735026918962584f * sp;   // sqrt(1/3) * spatial_weight
  alo[idx] = 0.5f * (1.f - tm);
  ahi[idx] = 0.5f * (1.f + tm);
}

// ---------------------------------------------------------------------------
// forward grouped conv, channel-split partials (unchanged from R4).
// ---------------------------------------------------------------------------
__global__ __launch_bounds__(192) void conv_fwd_part_k(
    const float* __restrict__ feat, const float* __restrict__ wsrc,
    float* __restrict__ part)
{
  __shared__ __align__(16) float sfeat[8 * PLSZ];
  int tid = threadIdx.x;
  int n = blockIdx.x;
  int s = n & 63;
  int kc = blockIdx.y;
  const float* fbase = feat + ((size_t)n * C_CH + kc * CPB) * (H_IN * W_IN);
  const float* wbase = wsrc + ((size_t)s * C_CH + kc * CPB) * FT;

  for (int idx = tid; idx < 8 * PLSZ; idx += 192) sfeat[idx] = 0.f;

  int ch_l = tid / 24;
  int row_l = tid - ch_l * 24;
  bool stager = row_l < 18;

  int pos = tid >> 3;
  int slot = tid & 7;
  bool act = pos < 20;
  int cpos = act ? pos : 19;
  int ty = cpos / 5, tx = cpos - (cpos / 5) * 5;

  float acc[5][4];
  #pragma unroll
  for (int r = 0; r < 5; ++r)
    #pragma unroll
    for (int c = 0; c < 4; ++c) acc[r][c] = 0.f;

  const float* plane0 = &sfeat[slot * PLSZ + (5 * ty) * PLW + 4 * tx];
  __syncthreads();

  for (int c0 = 0; c0 < CPB; c0 += 8) {
    if (stager) {
      const float* src = fbase + (size_t)(c0 + ch_l) * (H_IN * W_IN) + row_l * W_IN;
      float* dst = &sfeat[ch_l * PLSZ + (row_l + 2) * PLW + 2];
      #pragma unroll
      for (int k = 0; k < 9; ++k) {
        float2 v = *(const float2*)(src + 2 * k);
        *(float2*)(dst + 2 * k) = v;
      }
    }
    __syncthreads();

    const float4* wp = (const float4*)(wbase + (size_t)(c0 + slot) * FT);
    float4 w0 = wp[0], w1 = wp[1], w2 = wp[2], w3 = wp[3];

    #pragma unroll
    for (int ri = 0; ri < 8; ++ri) {
      float4 ra = *(const float4*)(plane0 + ri * PLW);
      float4 rb = *(const float4*)(plane0 + ri * PLW + 4);
      #pragma unroll
      for (int dy = 0; dy < 4; ++dy) {
        int r = ri - dy;
        if (r < 0 || r > 4) continue;
        float4 wr = (dy == 0) ? w0 : (dy == 1) ? w1 : (dy == 2) ? w2 : w3;
        acc[r][0] = fmaf(ra.x, wr.x, acc[r][0]); acc[r][0] = fmaf(ra.y, wr.y, acc[r][0]);
        acc[r][0] = fmaf(ra.z, wr.z, acc[r][0]); acc[r][0] = fmaf(ra.w, wr.w, acc[r][0]);
        acc[r][1] = fmaf(ra.y, wr.x, acc[r][1]); acc[r][1] = fmaf(ra.z, wr.y, acc[r][1]);
        acc[r][1] = fmaf(ra.w, wr.z, acc[r][1]); acc[r][1] = fmaf(rb.x, wr.w, acc[r][1]);
        acc[r][2] = fmaf(ra.z, wr.x, acc[r][2]); acc[r][2] = fmaf(ra.w, wr.y, acc[r][2]);
        acc[r][2] = fmaf(rb.x, wr.z, acc[r][2]); acc[r][2] = fmaf(rb.y, wr.w, acc[r][2]);
        acc[r][3] = fmaf(ra.w, wr.x, acc[r][3]); acc[r][3] = fmaf(rb.x, wr.y, acc[r][3]);
        acc[r][3] = fmaf(rb.y, wr.z, acc[r][3]); acc[r][3] = fmaf(rb.z, wr.w, acc[r][3]);
      }
    }
    __syncthreads();
  }

  #pragma unroll
  for (int r = 0; r < 5; ++r)
    #pragma unroll
    for (int c = 0; c < 4; ++c) {
      float v = acc[r][c];
      v += __shfl_xor(v, 1, 64);
      v += __shfl_xor(v, 2, 64);
      v += __shfl_xor(v, 4, 64);
      acc[r][c] = v;
    }

  int orow = 5 * ty + slot;
  if (act && slot < 5 && orow < OH) {
    float4 v = make_float4(acc[slot][0], acc[slot][1], acc[slot][2], acc[slot][3]);
    *(float4*)(part + ((size_t)n * CSPLIT + kc) * PPIX + orow * 20 + 4 * tx) = v;
  }
}

// ---------------------------------------------------------------------------
// combine0 (iter 1 only): sum partials -> scores buffer + mask + residuals
// ---------------------------------------------------------------------------
__global__ __launch_bounds__(384) void combine0_k(
    const float* __restrict__ part,
    const float* __restrict__ sw, const float* __restrict__ lm,
    const float* __restrict__ alo, const float* __restrict__ ahi,
    float* __restrict__ scores,
    float* __restrict__ mask, float* __restrict__ rbuf)
{
  int n = blockIdx.x;
  int p = threadIdx.x;
  if (p >= NPIX) return;
  int y = p / OW, x = p - y * OW;
  const float* pb = part + (size_t)n * CSPLIT * PPIX + y * 20 + x;
  float sv = 0.f;
  #pragma unroll
  for (int k = 0; k < CSPLIT; ++k) sv += pb[k * PPIX];
  int idx = n * NPIX + p;
  scores[idx] = sv;
  float lo = alo[idx], hi = ahi[idx], s_w = sw[idx], l_v = lm[idx];
  float sgn = (sv > 0.f) ? 1.f : ((sv < 0.f) ? -1.f : 0.f);
  float actv = lo * fabsf(sv) + hi * sv;
  float msk = lo * sgn + hi;
  mask[idx] = msk;
  rbuf[idx] = msk * s_w * s_w * (actv - l_v);
}

// ---------------------------------------------------------------------------
// transpose conv (unchanged from R4)
// ---------------------------------------------------------------------------
__global__ __launch_bounds__(192) void conv_tr_k(
    const float* __restrict__ feat, const float* __restrict__ r,
    const float* __restrict__ wcur, const float* __restrict__ scal,
    float* __restrict__ wg, float* __restrict__ num_part)
{
  __shared__ __align__(16) float rp[3 * RPSZ];
  __shared__ float swg[3 * 64 * FT];
  __shared__ float rtmp[3];
  int tid = threadIdx.x;
  int s = blockIdx.y;
  int cblk = blockIdx.x;
  int i = tid >> 6;
  int cl = tid & 63;
  int c = cblk * 64 + cl;

  for (int idx = tid; idx < 3 * RPSZ; idx += 192) rp[idx] = 0.f;
  __syncthreads();
  for (int idx = tid; idx < 3 * NPIX; idx += 192) {
    int ii = idx / NPIX, p = idx - ii * NPIX;
    int y = p / OW, x = p - y * OW;
    rp[ii * RPSZ + (y + 1) * RPW + (x + 1)] = r[(size_t)(ii * S_SEQ + s) * NPIX + p];
  }
  __syncthreads();

  const float* plane = &rp[i * RPSZ];
  const float* fpl = feat + (size_t)((i * S_SEQ + s) * C_CH + c) * (H_IN * W_IN);

  float acc[FT];
  #pragma unroll
  for (int t = 0; t < FT; ++t) acc[t] = 0.f;

  for (int u = 0; u < H_IN; ++u) {
    const float* frow = fpl + u * W_IN;
    const float* prow = plane + (u + 3) * RPW;
    #pragma unroll
    for (int st = 0; st < 2; ++st) {
      int v0 = st * 8;
      float f[8];
      #pragma unroll
      for (int k = 0; k < 4; ++k) {
        float2 v = *(const float2*)(frow + v0 + 2 * k);
        f[2 * k] = v.x; f[2 * k + 1] = v.y;
      }
      #pragma unroll
      for (int dy = 0; dy < 4; ++dy) {
        const float* rr = prow - dy * RPW + v0;
        float4 s0 = *(const float4*)(rr);
        float4 s1 = *(const float4*)(rr + 4);
        float4 s2 = *(const float4*)(rr + 8);
        float seg[12] = {s0.x, s0.y, s0.z, s0.w, s1.x, s1.y, s1.z, s1.w,
                         s2.x, s2.y, s2.z, s2.w};
        #pragma unroll
        for (int dx = 0; dx < 4; ++dx) {
          float a = acc[dy * 4 + dx];
          #pragma unroll
          for (int j = 0; j < 8; ++j) a = fmaf(f[j], seg[j + 3 - dx], a);
          acc[dy * 4 + dx] = a;
        }
      }
    }
    {
      float2 ft = *(const float2*)(frow + 16);
      #pragma unroll
      for (int dy = 0; dy < 4; ++dy) {
        const float* rr = prow - dy * RPW + 16;
        float4 s0 = *(const float4*)(rr);
        float4 s1 = *(const float4*)(rr + 4);
        float seg[8] = {s0.x, s0.y, s0.z, s0.w, s1.x, s1.y, s1.z, s1.w};
        #pragma unroll
        for (int dx = 0; dx < 4; ++dx) {
          float a = acc[dy * 4 + dx];
          a = fmaf(ft.x, seg[3 - dx], a);
          a = fmaf(ft.y, seg[4 - dx], a);
          acc[dy * 4 + dx] = a;
        }
      }
    }
  }

  #pragma unroll
  for (int t = 0; t < FT; ++t) swg[(i * 64 + cl) * FT + t] = acc[t];
  __syncthreads();

  float regv = scal[1];
  float sq = 0.f;
  for (int g = tid; g < 64 * FT; g += 192) {
    int cc = g >> 4, t = g & 15;
    float v = swg[cc * FT + t] + swg[(64 + cc) * FT + t] + swg[(128 + cc) * FT + t];
    size_t widx = ((size_t)s * C_CH + cblk * 64 + cc) * FT + t;
    v += regv * wcur[widx];
    wg[widx] = v;
    sq += v * v;
  }
  float tot = blk_reduce(sq, rtmp);
  if (tid == 0) num_part[s * 8 + cblk] = tot;
}

// ---------------------------------------------------------------------------
// update: den from sg partials, alpha, weight step, INCREMENTAL scores update,
// and next-iteration mask/residuals (fused combine0).
// block = s, 256 threads.
// ---------------------------------------------------------------------------
__global__ __launch_bounds__(256) void update_k(
    float* __restrict__ wcur, const float* __restrict__ wg,
    const float* __restrict__ partb,
    const float* __restrict__ sw, const float* __restrict__ lm,
    const float* __restrict__ alo, const float* __restrict__ ahi,
    float* __restrict__ scores, float* __restrict__ mask,
    float* __restrict__ rbuf,
    const float* __restrict__ num_part, const float* __restrict__ scal)
{
  __shared__ float rtmp[4];
  __shared__ float s_sa;
  int s = blockIdx.x;
  int tid = threadIdx.x;

  // Phase A: sg = sum of partials; den = sum (sw*mask*sg)^2. Keep sg in regs.
  float sgl[5];
  float sq = 0.f;
  #pragma unroll
  for (int k = 0; k < 5; ++k) {
    int g = tid + k * 256;
    sgl[k] = 0.f;
    if (g < I_IMG * NPIX) {
      int i = g / NPIX, p = g - i * NPIX;
      int n = i * S_SEQ + s;
      int y = p / OW, x = p - y * OW;
      const float* pb = partb + (size_t)n * CSPLIT * PPIX + y * 20 + x;
      float sv = 0.f;
      #pragma unroll
      for (int kk = 0; kk < CSPLIT; ++kk) sv += pb[kk * PPIX];
      sgl[k] = sv;
      int idx = n * NPIX + p;
      float sg = sw[idx] * mask[idx] * sv;
      sq += sg * sg;
    }
  }
  float den = blk_reduce(sq, rtmp);
  if (tid == 0) {
    float num = 0.f;
    #pragma unroll
    for (int k = 0; k < 8; ++k) num += num_part[s * 8 + k];
    float regv = scal[1], step = scal[0];
    float d = fmaxf(den + regv * num, 1e-8f);
    s_sa = step * (num / d);
  }
  __syncthreads();
  float sa = s_sa;

  // Phase B: weight step
  float4* w4 = (float4*)(wcur + (size_t)s * (C_CH * FT));
  const float4* g4 = (const float4*)(wg + (size_t)s * (C_CH * FT));
  for (int idx = tid; idx < C_CH * FT / 4; idx += 256) {
    float4 w = w4[idx], g = g4[idx];
    w.x -= sa * g.x; w.y -= sa * g.y; w.z -= sa * g.z; w.w -= sa * g.w;
    w4[idx] = w;
  }

  // Phase C: incremental scores update + next mask/residuals
  #pragma unroll
  for (int k = 0; k < 5; ++k) {
    int g = tid + k * 256;
    if (g < I_IMG * NPIX) {
      int i = g / NPIX, p = g - i * NPIX;
      int idx = (i * S_SEQ + s) * NPIX + p;
      float sv = scores[idx] - sa * sgl[k];
      scores[idx] = sv;
      float lo = alo[idx], hi = ahi[idx], s_w = sw[idx], l_v = lm[idx];
      float sgn = (sv > 0.f) ? 1.f : ((sv < 0.f) ? -1.f : 0.f);
      float actv = lo * fabsf(sv) + hi * sv;
      float msk = lo * sgn + hi;
      mask[idx] = msk;
      rbuf[idx] = msk * s_w * s_w * (actv - l_v);
    }
  }
}

// ---------------------------------------------------------------------------
extern "C" void kernel_launch(void* const* d_in, const int* in_sizes, int n_in,
                              void* d_out, int out_size, void* d_ws, size_t ws_size,
                              hipStream_t stream)
{
  const float* w_in = (const float*)d_in[0];
  const float* feat = (const float*)d_in[1];
  const float* bb   = (const float*)d_in[2];
  const float* lblw = (const float*)d_in[3];
  const float* mskw = (const float*)d_in[4];
  const float* spw  = (const float*)d_in[5];
  const float* lsl  = (const float*)d_in[6];
  const float* freg = (const float*)d_in[7];

  float* base = (float*)d_ws;
  const int NMAP = I_IMG * S_SEQ * NPIX;   // 69312
  const int NW   = S_SEQ * C_CH * FT;      // 524288
  float* sw     = base;
  float* lm     = sw + NMAP;
  float* alo    = lm + NMAP;
  float* ahi    = alo + NMAP;
  float* mask   = ahi + NMAP;
  float* rbuf   = mask + NMAP;
  float* scores = rbuf + NMAP;
  float* wcur   = scores + NMAP;
  float* wg     = wcur + NW;
  float* nump   = wg + NW;
  float* scal   = nump + S_SEQ * 8;
  float* partb  = scal + 8;                // I*S*CSPLIT*PPIX = 614400

  prep_k<<<I_IMG * S_SEQ, 384, 0, stream>>>(bb, lblw, mskw, spw, lsl, freg,
                                            sw, lm, alo, ahi, scal);
  hipMemcpyAsync(wcur, w_in, (size_t)NW * sizeof(float),
                 hipMemcpyDeviceToDevice, stream);

  // initial scores pass (only full forward conv of w)
  conv_fwd_part_k<<<dim3(I_IMG * S_SEQ, CSPLIT), 192, 0, stream>>>(
      feat, wcur, partb);
  combine0_k<<<I_IMG * S_SEQ, 384, 0, stream>>>(
      partb, sw, lm, alo, ahi, scores, mask, rbuf);

  for (int it = 0; it < NITER; ++it) {
    conv_tr_k<<<dim3(8, S_SEQ), 192, 0, stream>>>(
        feat, rbuf, wcur, scal, wg, nump);
    conv_fwd_part_k<<<dim3(I_IMG * S_SEQ, CSPLIT), 192, 0, stream>>>(
        feat, wg, partb);
    update_k<<<S_SEQ, 256, 0, stream>>>(
        wcur, wg, partb, sw, lm, alo, ahi, scores, mask, rbuf, nump, scal);
  }
  hipMemcpyAsync(d_out, wcur, (size_t)NW * sizeof(float),
                 hipMemcpyDeviceToDevice, stream);
}